// Round 10
// baseline (483.449 us; speedup 1.0000x reference)
//
#include <hip/hip_runtime.h>

#define NPTS 8192
#define NB 4
#define KNN 16
#define DCH 64
#define CAP 128
#define WR 8
#define G 32
#define NC 32768          // G^3 cells
#define MCAP 2048         // staged-stream capacity per wave
#define HCEL 0.3125f      // 10/G

// ws layout (bytes):
//   xq    : float4[NB*NPTS]      @ 0        (524288)  raw (x,y,z,|x|^2), ORIG order (k2 queries, k3, k5)
//   xss   : float4[NB*NPTS]      @ 524288   (524288)  scaled (-2x,-2y,-2z,|x|^2), CELL-SORTED order
//   oidx  : ushort[NB*NPTS]      @ 1048576  (65536)   sorted pos -> orig local idx
//   ibuf  : ushort[NB*NPTS][16]  @ 1114112  (1048576) final knn orig ids per ORIG row
//   cellP : int[NB*NC]           @ 2162688  (524288)  histogram -> exclusive prefix -> (post-scatter) inclusive ends
//   stats : double[54]           @ 2686976  (pad 512)
//   ss    : float[128]           @ 2687488
#define WS_XQ 0
#define WS_XS 524288
#define WS_OI 1048576
#define WS_IB 1114112
#define WS_CP 2162688
#define WS_ST 2686976
#define WS_SS 2687488

// v = -2*dot(q,c) + |c|^2 on prescaled candidate; d = v + |q|^2 (row-const) => same ranking.
__device__ __forceinline__ float vkey(float4 q, float4 c) {
    return __fmaf_rn(q.x, c.x, __fmaf_rn(q.y, c.y, __fmaf_rn(q.z, c.z, c.w)));
}

// identical in k1/k0c/k2 (monotone, clamped)
__device__ __forceinline__ int cellof(float v) {
    float t = (v + 5.0f) * 3.2f;
    t = fminf(fmaxf(t, 0.0f), 31.0f);
    return (int)t;
}

__global__ __launch_bounds__(256) void k1_prep(const float* __restrict__ x, float4* __restrict__ xq,
                                               int* __restrict__ cellP) {
    int p = blockIdx.x * 256 + threadIdx.x;
    if (p >= NB * NPTS) return;
    int b = p >> 13;
    float x0 = x[p * 3 + 0], x1 = x[p * 3 + 1], x2 = x[p * 3 + 2];
    float sq = __fmaf_rn(x0, x0, __fmaf_rn(x1, x1, x2 * x2));
    xq[p] = make_float4(x0, x1, x2, sq);
    int cid = (cellof(x2) * G + cellof(x1)) * G + cellof(x0);   // x fastest
    atomicAdd(&cellP[b * NC + cid], 1);
}

// exclusive prefix per batch: 1024 threads x 32 bins
__global__ __launch_bounds__(1024) void k0b_prefix(int* __restrict__ P) {
    __shared__ int part[1024];
    int t = threadIdx.x;
    int* Pb = P + blockIdx.x * NC;
    int loc[32];
    int s = 0;
    int base = t * 32;
#pragma unroll
    for (int i = 0; i < 32; ++i) { loc[i] = Pb[base + i]; s += loc[i]; }
    part[t] = s;
    __syncthreads();
    for (int off = 1; off < 1024; off <<= 1) {
        int v = part[t];
        if (t >= off) v += part[t - off];
        __syncthreads();
        part[t] = v;
        __syncthreads();
    }
    int run = (t == 0) ? 0 : part[t - 1];
#pragma unroll
    for (int i = 0; i < 32; ++i) { int c = loc[i]; Pb[base + i] = run; run += c; }
}

// scatter into cell order; converts cellP to inclusive ends. Intra-cell order is
// nondeterministic (atomics) but all consumers are order-invariant sets.
__global__ __launch_bounds__(256) void k0c_scatter(const float* __restrict__ x, int* __restrict__ cellP,
                                                   float4* __restrict__ xss, unsigned short* __restrict__ oidx) {
    int p = blockIdx.x * 256 + threadIdx.x;
    if (p >= NB * NPTS) return;
    int b = p >> 13, pl = p & (NPTS - 1);
    float x0 = x[p * 3 + 0], x1 = x[p * 3 + 1], x2 = x[p * 3 + 2];
    float sq = __fmaf_rn(x0, x0, __fmaf_rn(x1, x1, x2 * x2));
    int cid = (cellof(x2) * G + cellof(x1)) * G + cellof(x0);
    int pos = atomicAdd(&cellP[b * NC + cid], 1);
    xss[b * NPTS + pos] = make_float4(-2.0f * x0, -2.0f * x1, -2.0f * x2, sq);
    oidx[b * NPTS + pos] = (unsigned short)pl;
}

// Exact KNN over a spatially pruned candidate stream.
// tau0 (bound): 16th smallest v of 64 sorted-adjacent candidates -> window radius.
// stage: walk window cells once, compact candidate sorted-indices densely into LDS.
//        overflow (M>MCAP, rare straddle waves) -> full-range fallback (fb).
// passA: lane minima over stream -> exact 16th-of-64 rank-count tau (tight; stream
//        contains the true top-16, so d16(stream)=d16(full) and tau>=d16).
// passB: ballot-append all v<=tau with ORIG idx.  phase3: exact (v,orig) top-16.
__global__ __launch_bounds__(256, 3) void k2_knn(const float4* __restrict__ xq,
                                                 const float4* __restrict__ xss,
                                                 const unsigned short* __restrict__ oidx,
                                                 const int* __restrict__ cellP,
                                                 unsigned short* __restrict__ ibuf) {
    __shared__ float2 buf[4][WR][CAP];        // 32 KB (also aliased as tau scratch)
    __shared__ unsigned short sidx[4][MCAP];  // 16 KB
    const int wave = threadIdx.x >> 6;
    const int lane = threadIdx.x & 63;
    const int b = blockIdx.x >> 8;
    const int js = (blockIdx.x & 255) * 32 + wave * WR;   // sorted row base within batch
    const float4* xqb = xq + b * NPTS;
    const float4* xsb = xss + b * NPTS;
    const unsigned short* oib = oidx + b * NPTS;
    const int* Pb = cellP + b * NC;
    float* vw = (float*)&buf[wave][0][0];    // [r*64+lane] scratch, wave-private

    float4 xi[WR];
    int orow[WR];
#pragma unroll
    for (int r = 0; r < WR; ++r) {
        int o = oib[js + r];
        orow[r] = o;
        xi[r] = xqb[o];
    }

    // wave bbox over the 8 queries
    float bxl = xi[0].x, bxh = xi[0].x, byl = xi[0].y, byh = xi[0].y, bzl = xi[0].z, bzh = xi[0].z;
#pragma unroll
    for (int r = 1; r < WR; ++r) {
        bxl = fminf(bxl, xi[r].x); bxh = fmaxf(bxh, xi[r].x);
        byl = fminf(byl, xi[r].y); byh = fmaxf(byh, xi[r].y);
        bzl = fminf(bzl, xi[r].z); bzh = fmaxf(bzh, xi[r].z);
    }

    // ---- tau0: 16th smallest v over 64 sorted-adjacent candidates ----
    int w0 = js - 28;
    w0 = w0 < 0 ? 0 : (w0 > NPTS - 64 ? NPTS - 64 : w0);
    float4 cw = xsb[w0 + lane];
    float v0s[WR];
#pragma unroll
    for (int r = 0; r < WR; ++r) { v0s[r] = vkey(xi[r], cw); vw[r * 64 + lane] = v0s[r]; }
    __syncthreads();
    float taudmax = 0.0f;
#pragma unroll
    for (int r = 0; r < WR; ++r) {
        float mine = v0s[r];
        int rk = 0;
        const float4* vm4 = (const float4*)(vw + r * 64);
#pragma unroll
        for (int q = 0; q < 16; ++q) {
            float4 vv = vm4[q];
            int j0 = q * 4;
            rk += (vv.x < mine || (vv.x == mine && (j0 + 0) < lane)) ? 1 : 0;
            rk += (vv.y < mine || (vv.y == mine && (j0 + 1) < lane)) ? 1 : 0;
            rk += (vv.z < mine || (vv.z == mine && (j0 + 2) < lane)) ? 1 : 0;
            rk += (vv.w < mine || (vv.w == mine && (j0 + 3) < lane)) ? 1 : 0;
        }
        float v = (rk < KNN) ? mine : -3.0e38f;
#pragma unroll
        for (int o = 32; o > 0; o >>= 1) v = fmaxf(v, __shfl_xor(v, o));
        taudmax = fmaxf(taudmax, v + xi[r].w);   // tau_d = tau_v + |q|^2
    }
    taudmax = fmaxf(taudmax, 0.0f);
    float rmax = sqrtf(taudmax);

    int cx0 = cellof(bxl - rmax), cx1 = cellof(bxh + rmax);
    int cy0 = cellof(byl - rmax), cy1 = cellof(byh + rmax);
    int cz0 = cellof(bzl - rmax), cz1 = cellof(bzh + rmax);

    // ---- stage: walk cells once, compact stream (dense) ----
    int M = 0;
    for (int iz = cz0; iz <= cz1; ++iz) {
        float zl = (iz == 0) ? -1.0e30f : (-5.0f + iz * HCEL);
        float zh = (iz == G - 1) ? 1.0e30f : (-5.0f + (iz + 1) * HCEL);
        float dz = fmaxf(0.0f, fmaxf(zl - bzh, bzl - zh));
        float dz2 = dz * dz;
        if (dz2 > taudmax) continue;
        for (int iy = cy0; iy <= cy1; ++iy) {
            float yl = (iy == 0) ? -1.0e30f : (-5.0f + iy * HCEL);
            float yh = (iy == G - 1) ? 1.0e30f : (-5.0f + (iy + 1) * HCEL);
            float dy = fmaxf(0.0f, fmaxf(yl - byh, byl - yh));
            float dd = __fmaf_rn(dy, dy, dz2);
            if (dd > taudmax) continue;
            int cb = (iz * G + iy) * G;
            int cs = cb + cx0, ce = cb + cx1;
            int s0 = (cs == 0) ? 0 : Pb[cs - 1];
            int e0 = Pb[ce];
            for (int q0 = s0; q0 < e0; q0 += 64) {
                int len = e0 - q0; len = len < 64 ? len : 64;
                int pos = M + lane;
                if (lane < len && pos < MCAP) sidx[wave][pos] = (unsigned short)(q0 + lane);
                M += len;
            }
        }
    }
    __syncthreads();
    const bool fb = (M > MCAP);          // rare: fall back to full scan
    const int Ms = fb ? NPTS : M;        // Ms >= 16 always (stream contains each row's top-16)

    // ---- pass A: lane minima over the stream ----
    float mn[WR];
#pragma unroll
    for (int r = 0; r < WR; ++r) mn[r] = 3.0e38f;
    for (int q0 = 0; q0 < Ms; q0 += 64) {
        int t_ = q0 + lane;
        bool act = t_ < Ms;
        int idx = fb ? t_ : (int)sidx[wave][act ? t_ : 0];
        float4 c = act ? xsb[idx] : make_float4(0.0f, 0.0f, 0.0f, 3.0e38f);
#pragma unroll
        for (int r = 0; r < WR; ++r) mn[r] = fminf(mn[r], vkey(xi[r], c));
    }

    // ---- final tau: exact 16th smallest of the 64 lane-minima ----
#pragma unroll
    for (int r = 0; r < WR; ++r) vw[r * 64 + lane] = mn[r];
    __syncthreads();
    float tau[WR];
#pragma unroll
    for (int r = 0; r < WR; ++r) {
        float mine = mn[r];
        int rk = 0;
        const float4* vm4 = (const float4*)(vw + r * 64);
#pragma unroll
        for (int q = 0; q < 16; ++q) {
            float4 vv = vm4[q];
            int j0 = q * 4;
            rk += (vv.x < mine || (vv.x == mine && (j0 + 0) < lane)) ? 1 : 0;
            rk += (vv.y < mine || (vv.y == mine && (j0 + 1) < lane)) ? 1 : 0;
            rk += (vv.z < mine || (vv.z == mine && (j0 + 2) < lane)) ? 1 : 0;
            rk += (vv.w < mine || (vv.w == mine && (j0 + 3) < lane)) ? 1 : 0;
        }
        float v = (rk < KNN) ? mine : -3.0e38f;
#pragma unroll
        for (int o = 32; o > 0; o >>= 1) v = fmaxf(v, __shfl_xor(v, o));
        tau[r] = v;
    }

    // ---- pass B: ballot-append (v, orig) for v <= tau ----
    int cnt[WR];
#pragma unroll
    for (int r = 0; r < WR; ++r) cnt[r] = 0;
    for (int q0 = 0; q0 < Ms; q0 += 64) {
        int t_ = q0 + lane;
        bool act = t_ < Ms;
        int idx = fb ? t_ : (int)sidx[wave][act ? t_ : 0];
        float4 c = act ? xsb[idx] : make_float4(0.0f, 0.0f, 0.0f, 3.0e38f);
        float fo = act ? (float)oib[idx] : 0.0f;
#pragma unroll
        for (int r = 0; r < WR; ++r) {
            float v = vkey(xi[r], c);     // inactive -> 3e38, fails filter
            bool p = (v <= tau[r]);
            unsigned long long m = __ballot(p);
            if (m) {
                if (p) {
                    int ofs = __builtin_amdgcn_mbcnt_hi((unsigned)(m >> 32),
                              __builtin_amdgcn_mbcnt_lo((unsigned)m, 0));
                    int pos = cnt[r] + ofs;
                    if (pos < CAP) buf[wave][r][pos] = make_float2(v, fo);
                }
                cnt[r] += (int)__popcll(m);
            }
        }
    }

    __syncthreads();

    // ---- phase 3: exact top-16 by (v, orig) rank count ----
#pragma unroll
    for (int rr = 0; rr < WR; ++rr) {
        int n = cnt[rr];
        n = (n < CAP) ? n : CAP;
        int l1 = lane + 64;
        bool v0 = (lane < n), v1 = (l1 < n);
        float2 e0 = buf[wave][rr][v0 ? lane : 0];
        float2 e1 = buf[wave][rr][v1 ? l1 : 0];
        int r0 = 0, r1 = 0;
        for (int j = 0; j < n; ++j) {
            float2 fj = buf[wave][rr][j];
            r0 += (fj.x < e0.x || (fj.x == e0.x && fj.y < e0.y)) ? 1 : 0;
            r1 += (fj.x < e1.x || (fj.x == e1.x && fj.y < e1.y)) ? 1 : 0;
        }
        size_t grow = (size_t)(b * NPTS + orow[rr]) * KNN;
        if (v0 && r0 < KNN) ibuf[grow + r0] = (unsigned short)(int)e0.y;
        if (v1 && r1 < KNN) ibuf[grow + r1] = (unsigned short)(int)e1.y;
    }
}

// moments over the 16 selected neighbors: acc[0..8]=sum f, acc[9..53]=sum f_a f_c (upper tri)
__global__ __launch_bounds__(256) void k3_moments(const float4* __restrict__ xq,
                                                  const unsigned short* __restrict__ ibuf,
                                                  double* __restrict__ stats) {
    __shared__ float red[4][54];
    int p = blockIdx.x * 256 + threadIdx.x;
    int b = p >> 13;
    const float4* xb = xq + b * NPTS;
    const unsigned short* ib = ibuf + (size_t)p * KNN;
    float4 xi = xb[p & (NPTS - 1)];

    float acc[54];
#pragma unroll
    for (int i = 0; i < 54; ++i) acc[i] = 0.0f;

#pragma unroll
    for (int k = 0; k < KNN; ++k) {
        int j = ib[k];
        float4 cj = xb[j];
        float f[9] = {xi.x, xi.y, xi.z, cj.x - xi.x, cj.y - xi.y, cj.z - xi.z, cj.x, cj.y, cj.z};
        int t = 9;
#pragma unroll
        for (int a = 0; a < 9; ++a) {
            acc[a] += f[a];
#pragma unroll
            for (int c = a; c < 9; ++c) { acc[t] += f[a] * f[c]; ++t; }
        }
    }

#pragma unroll
    for (int i = 0; i < 54; ++i) {
        float v = acc[i];
        for (int o = 32; o > 0; o >>= 1) v += __shfl_down(v, o);
        acc[i] = v;
    }
    int lane = threadIdx.x & 63;
    int wv = threadIdx.x >> 6;
    if (lane == 0) {
#pragma unroll
        for (int i = 0; i < 54; ++i) red[wv][i] = acc[i];
    }
    __syncthreads();
    if (threadIdx.x < 54) {
        float s = red[0][threadIdx.x] + red[1][threadIdx.x] + red[2][threadIdx.x] + red[3][threadIdx.x];
        atomicAdd(&stats[threadIdx.x], (double)s);
    }
}

__global__ void k4_finalize(const double* __restrict__ stats, const float* __restrict__ W,
                            const float* __restrict__ bias, const float* __restrict__ gamma,
                            const float* __restrict__ beta, float* __restrict__ ss) {
    int d = threadIdx.x;
    if (d >= DCH) return;
    const double M = (double)NB * NPTS * KNN;  // 524288
    double w[9];
    for (int c = 0; c < 9; ++c) w[c] = (double)W[c * DCH + d];
    double mf[9];
    for (int a = 0; a < 9; ++a) mf[a] = stats[a] / M;
    double q1 = 0.0;
    for (int a = 0; a < 9; ++a) q1 += mf[a] * w[a];
    double q2 = 0.0;
    int t = 0;
    for (int a = 0; a < 9; ++a) {
        for (int c = a; c < 9; ++c) {
            double pv = stats[9 + t] / M;
            double term = pv * w[a] * w[c];
            q2 += (a == c) ? term : 2.0 * term;
            ++t;
        }
    }
    double bd = (double)bias[d];
    double mean = q1 + bd;
    double ehh = q2 + 2.0 * bd * q1 + bd * bd;
    double var = ehh - mean * mean;
    double sc = (double)gamma[d] / sqrt(var + 1e-5);
    double sh = (double)beta[d] + sc * (bd - mean);
    ss[d] = (float)sc;
    ss[DCH + d] = (float)sh;
}

// 8 threads per point, 8 channels each: h = f.W (W in regs), y = max_k relu(sc*h+sh)
__global__ __launch_bounds__(256) void k5_out(const float4* __restrict__ xq,
                                              const unsigned short* __restrict__ ibuf,
                                              const float* __restrict__ W, const float* __restrict__ ss,
                                              float* __restrict__ out) {
    __shared__ float Ws[9 * DCH];
    __shared__ float scs[DCH], shs[DCH];
    for (int i = threadIdx.x; i < 9 * DCH; i += 256) Ws[i] = W[i];
    if (threadIdx.x < DCH) {
        scs[threadIdx.x] = ss[threadIdx.x];
        shs[threadIdx.x] = ss[DCH + threadIdx.x];
    }
    __syncthreads();

    int pt = blockIdx.x * 32 + (threadIdx.x >> 3);
    int oc = (threadIdx.x & 7) * 8;
    int b = pt >> 13;
    const float4* xb = xq + b * NPTS;
    float4 xi = xb[pt & (NPTS - 1)];

    float w[9][8];
#pragma unroll
    for (int c = 0; c < 9; ++c)
#pragma unroll
        for (int d = 0; d < 8; ++d) w[c][d] = Ws[c * DCH + oc + d];
    float sc[8], sh[8], y[8];
#pragma unroll
    for (int d = 0; d < 8; ++d) {
        sc[d] = scs[oc + d];
        sh[d] = shs[oc + d];
        y[d] = 0.0f;
    }

    const unsigned short* ib = ibuf + (size_t)pt * KNN;
#pragma unroll
    for (int k = 0; k < KNN; ++k) {
        int j = ib[k];
        float4 cj = xb[j];
        float f[9] = {xi.x, xi.y, xi.z, cj.x - xi.x, cj.y - xi.y, cj.z - xi.z, cj.x, cj.y, cj.z};
        float h[8];
#pragma unroll
        for (int d = 0; d < 8; ++d) h[d] = 0.0f;
#pragma unroll
        for (int c = 0; c < 9; ++c)
#pragma unroll
            for (int d = 0; d < 8; ++d) h[d] = __fmaf_rn(f[c], w[c][d], h[d]);
#pragma unroll
        for (int d = 0; d < 8; ++d) {
            float v = __fmaf_rn(sc[d], h[d], sh[d]);
            y[d] = fmaxf(y[d], fmaxf(v, 0.0f));
        }
    }
    float4* o4 = (float4*)(out + (size_t)pt * DCH + oc);
    o4[0] = make_float4(y[0], y[1], y[2], y[3]);
    o4[1] = make_float4(y[4], y[5], y[6], y[7]);
}

extern "C" void kernel_launch(void* const* d_in, const int* in_sizes, int n_in,
                              void* d_out, int out_size, void* d_ws, size_t ws_size,
                              hipStream_t stream) {
    const float* x = (const float*)d_in[0];
    const float* W = (const float*)d_in[1];
    const float* bias = (const float*)d_in[2];
    const float* gamma = (const float*)d_in[3];
    const float* beta = (const float*)d_in[4];
    float* out = (float*)d_out;
    char* ws = (char*)d_ws;

    float4* xq = (float4*)(ws + WS_XQ);
    float4* xss = (float4*)(ws + WS_XS);
    unsigned short* oidx = (unsigned short*)(ws + WS_OI);
    unsigned short* ibuf = (unsigned short*)(ws + WS_IB);
    int* cellP = (int*)(ws + WS_CP);
    double* stats = (double*)(ws + WS_ST);
    float* ss = (float*)(ws + WS_SS);

    hipMemsetAsync(cellP, 0, NB * NC * sizeof(int), stream);
    hipMemsetAsync(stats, 0, 54 * sizeof(double), stream);
    k1_prep<<<128, 256, 0, stream>>>(x, xq, cellP);
    k0b_prefix<<<NB, 1024, 0, stream>>>(cellP);
    k0c_scatter<<<128, 256, 0, stream>>>(x, cellP, xss, oidx);
    k2_knn<<<1024, 256, 0, stream>>>(xq, xss, oidx, cellP, ibuf);
    k3_moments<<<128, 256, 0, stream>>>(xq, ibuf, stats);
    k4_finalize<<<1, 64, 0, stream>>>(stats, W, bias, gamma, beta, ss);
    k5_out<<<1024, 256, 0, stream>>>(xq, ibuf, W, ss, out);
}

// Round 11
// 303.030 us; speedup vs baseline: 1.5954x; 1.5954x over previous
//
#include <hip/hip_runtime.h>

#define NPTS 8192
#define NB 4
#define KNN 16
#define DCH 64
#define CAP 128
#define WR 8
#define G 32
#define NC 32768          // G^3 cells
#define MCAP 2048         // staged-stream capacity per wave
#define SEGCAP 128
#define HCEL 0.3125f      // 10/G

// ws layout (bytes):
//   xq    : float4[NB*NPTS]      @ 0        (524288)  raw (x,y,z,|x|^2), ORIG order
//   xss   : float4[NB*NPTS]      @ 524288   (524288)  scaled (-2x,-2y,-2z,|x|^2), CELL-SORTED
//   oidx  : ushort[NB*NPTS]      @ 1048576  (65536)   sorted pos -> orig local idx
//   ibuf  : ushort[NB*NPTS][16]  @ 1114112  (1048576) final knn orig ids per ORIG row
//   cellP : int[NB*NC]           @ 2162688  (524288)  hist -> excl prefix -> inclusive ends
//   stats : double[54]           @ 2686976  (pad 512)
//   ss    : float[128]           @ 2687488
#define WS_XQ 0
#define WS_XS 524288
#define WS_OI 1048576
#define WS_IB 1114112
#define WS_CP 2162688
#define WS_ST 2686976
#define WS_SS 2687488

__device__ __forceinline__ float vkey(float4 q, float4 c) {
    return __fmaf_rn(q.x, c.x, __fmaf_rn(q.y, c.y, __fmaf_rn(q.z, c.z, c.w)));
}

__device__ __forceinline__ int cellof(float v) {
    float t = (v + 5.0f) * 3.2f;
    t = fminf(fmaxf(t, 0.0f), 31.0f);
    return (int)t;
}

__device__ __forceinline__ int mbcnt64(unsigned long long m) {
    return __builtin_amdgcn_mbcnt_hi((unsigned)(m >> 32),
           __builtin_amdgcn_mbcnt_lo((unsigned)m, 0));
}

__global__ __launch_bounds__(256) void k1_prep(const float* __restrict__ x, float4* __restrict__ xq,
                                               int* __restrict__ cellP) {
    int p = blockIdx.x * 256 + threadIdx.x;
    if (p >= NB * NPTS) return;
    int b = p >> 13;
    float x0 = x[p * 3 + 0], x1 = x[p * 3 + 1], x2 = x[p * 3 + 2];
    float sq = __fmaf_rn(x0, x0, __fmaf_rn(x1, x1, x2 * x2));
    xq[p] = make_float4(x0, x1, x2, sq);
    int cid = (cellof(x2) * G + cellof(x1)) * G + cellof(x0);   // x fastest
    atomicAdd(&cellP[b * NC + cid], 1);
}

__global__ __launch_bounds__(1024) void k0b_prefix(int* __restrict__ P) {
    __shared__ int part[1024];
    int t = threadIdx.x;
    int* Pb = P + blockIdx.x * NC;
    int loc[32];
    int s = 0;
    int base = t * 32;
#pragma unroll
    for (int i = 0; i < 32; ++i) { loc[i] = Pb[base + i]; s += loc[i]; }
    part[t] = s;
    __syncthreads();
    for (int off = 1; off < 1024; off <<= 1) {
        int v = part[t];
        if (t >= off) v += part[t - off];
        __syncthreads();
        part[t] = v;
        __syncthreads();
    }
    int run = (t == 0) ? 0 : part[t - 1];
#pragma unroll
    for (int i = 0; i < 32; ++i) { int c = loc[i]; Pb[base + i] = run; run += c; }
}

__global__ __launch_bounds__(256) void k0c_scatter(const float* __restrict__ x, int* __restrict__ cellP,
                                                   float4* __restrict__ xss, unsigned short* __restrict__ oidx) {
    int p = blockIdx.x * 256 + threadIdx.x;
    if (p >= NB * NPTS) return;
    int b = p >> 13, pl = p & (NPTS - 1);
    float x0 = x[p * 3 + 0], x1 = x[p * 3 + 1], x2 = x[p * 3 + 2];
    float sq = __fmaf_rn(x0, x0, __fmaf_rn(x1, x1, x2 * x2));
    int cid = (cellof(x2) * G + cellof(x1)) * G + cellof(x0);
    int pos = atomicAdd(&cellP[b * NC + cid], 1);
    xss[b * NPTS + pos] = make_float4(-2.0f * x0, -2.0f * x1, -2.0f * x2, sq);
    oidx[b * NPTS + pos] = (unsigned short)pl;
}

// Exact KNN over a spatially pruned candidate stream (R10 semantics, staging parallelized).
// build: (iz,iy) rows assigned to LANES -> all prefix loads concurrent; ballot-compact
//        segment list (s0, base) with shfl prefix-sum of lens. Segments alias dead buf space.
// pack : segment-major LDS write burst -> dense sidx stream (no global latency).
// passes A/B + tau + phase3: identical to the R10-proven code; fallback to full scan
//        on Mtot>MCAP or nseg>SEGCAP.
__global__ __launch_bounds__(256, 3) void k2_knn(const float4* __restrict__ xq,
                                                 const float4* __restrict__ xss,
                                                 const unsigned short* __restrict__ oidx,
                                                 const int* __restrict__ cellP,
                                                 unsigned short* __restrict__ ibuf) {
    __shared__ float2 buf[4][WR][CAP];        // 32 KB; [0,2KB)/wave = vw scratch, [2,3.5KB)/wave = segs
    __shared__ unsigned short sidx[4][MCAP];  // 16 KB
    const int wave = threadIdx.x >> 6;
    const int lane = threadIdx.x & 63;
    const int b = blockIdx.x >> 8;
    const int js = (blockIdx.x & 255) * 32 + wave * WR;   // sorted row base
    const float4* xqb = xq + b * NPTS;
    const float4* xsb = xss + b * NPTS;
    const unsigned short* oib = oidx + b * NPTS;
    const int* Pb = cellP + b * NC;
    float* vw = (float*)&buf[wave][0][0];                       // 512 floats
    int* seg_s0 = (int*)((char*)&buf[wave][0][0] + 2048);       // 128 ints
    int* seg_ba = (int*)((char*)&buf[wave][0][0] + 2560);       // 128 ints

    float4 xi[WR];
    int orow[WR];
#pragma unroll
    for (int r = 0; r < WR; ++r) {
        int o = oib[js + r];
        orow[r] = o;
        xi[r] = xqb[o];
    }

    float bxl = xi[0].x, bxh = xi[0].x, byl = xi[0].y, byh = xi[0].y, bzl = xi[0].z, bzh = xi[0].z;
#pragma unroll
    for (int r = 1; r < WR; ++r) {
        bxl = fminf(bxl, xi[r].x); bxh = fmaxf(bxh, xi[r].x);
        byl = fminf(byl, xi[r].y); byh = fmaxf(byh, xi[r].y);
        bzl = fminf(bzl, xi[r].z); bzh = fmaxf(bzh, xi[r].z);
    }

    // ---- tau0: 16th smallest v over 64 sorted-adjacent candidates ----
    int w0 = js - 28;
    w0 = w0 < 0 ? 0 : (w0 > NPTS - 64 ? NPTS - 64 : w0);
    float4 cw = xsb[w0 + lane];
    float v0s[WR];
#pragma unroll
    for (int r = 0; r < WR; ++r) { v0s[r] = vkey(xi[r], cw); vw[r * 64 + lane] = v0s[r]; }
    __syncthreads();
    float taudmax = 0.0f;
#pragma unroll
    for (int r = 0; r < WR; ++r) {
        float mine = v0s[r];
        int rk = 0;
        const float4* vm4 = (const float4*)(vw + r * 64);
#pragma unroll
        for (int q = 0; q < 16; ++q) {
            float4 vv = vm4[q];
            int j0 = q * 4;
            rk += (vv.x < mine || (vv.x == mine && (j0 + 0) < lane)) ? 1 : 0;
            rk += (vv.y < mine || (vv.y == mine && (j0 + 1) < lane)) ? 1 : 0;
            rk += (vv.z < mine || (vv.z == mine && (j0 + 2) < lane)) ? 1 : 0;
            rk += (vv.w < mine || (vv.w == mine && (j0 + 3) < lane)) ? 1 : 0;
        }
        float v = (rk < KNN) ? mine : -3.0e38f;
#pragma unroll
        for (int o = 32; o > 0; o >>= 1) v = fmaxf(v, __shfl_xor(v, o));
        taudmax = fmaxf(taudmax, v + xi[r].w);
    }
    taudmax = fmaxf(taudmax, 0.0f);
    float rmax = sqrtf(taudmax);

    int cx0 = cellof(bxl - rmax), cx1 = cellof(bxh + rmax);
    int cy0 = cellof(byl - rmax), cy1 = cellof(byh + rmax);
    int cz0 = cellof(bzl - rmax), cz1 = cellof(bzh + rmax);
    int nyr = cy1 - cy0 + 1;
    int npairs = nyr * (cz1 - cz0 + 1);

    // ---- parallel segment build: one (iz,iy) row per lane ----
    int Mtot = 0, nseg = 0;
    for (int p0 = 0; p0 < npairs; p0 += 64) {
        int p = p0 + lane;
        int s0v = 0, len = 0;
        if (p < npairs) {
            int iz = cz0 + p / nyr;
            int iy = cy0 + p - (p / nyr) * nyr;
            float zl = (iz == 0) ? -1.0e30f : (-5.0f + iz * HCEL);
            float zh = (iz == G - 1) ? 1.0e30f : (-5.0f + (iz + 1) * HCEL);
            float dz = fmaxf(0.0f, fmaxf(zl - bzh, bzl - zh));
            float yl = (iy == 0) ? -1.0e30f : (-5.0f + iy * HCEL);
            float yh = (iy == G - 1) ? 1.0e30f : (-5.0f + (iy + 1) * HCEL);
            float dy = fmaxf(0.0f, fmaxf(yl - byh, byl - yh));
            float dd = __fmaf_rn(dy, dy, dz * dz);
            if (dd <= taudmax) {
                int cb = (iz * G + iy) * G;
                int cs = cb + cx0, ce = cb + cx1;
                s0v = (cs == 0) ? 0 : Pb[cs - 1];
                int e0 = Pb[ce];
                len = e0 - s0v;
            }
        }
        bool have = (len > 0);
        unsigned long long m = __ballot(have);
        if (m) {
            int plen = have ? len : 0;
            int scan = plen;                       // inclusive shfl scan
#pragma unroll
            for (int o = 1; o < 64; o <<= 1) {
                int u = __shfl_up(scan, o);
                if (lane >= o) scan += u;
            }
            if (have) {
                int si = nseg + mbcnt64(m);
                if (si < SEGCAP) { seg_s0[si] = s0v; seg_ba[si] = Mtot + (scan - plen); }
            }
            nseg += (int)__popcll(m);
            Mtot += __shfl(scan, 63);
        }
    }

    const bool fb = (Mtot > MCAP) || (nseg > SEGCAP);
    const int Ms = fb ? NPTS : Mtot;

    // ---- pack: segment-major LDS burst (no global latency) ----
    if (!fb) {
        for (int s = 0; s < nseg; ++s) {
            int s0v = seg_s0[s];
            int bs = seg_ba[s];
            int ls = ((s + 1 < nseg) ? seg_ba[s + 1] : Mtot) - bs;
            for (int t = lane; t < ls; t += 64) sidx[wave][bs + t] = (unsigned short)(s0v + t);
        }
    }
    __syncthreads();

    // ---- pass A: lane minima over the stream ----
    float mn[WR];
#pragma unroll
    for (int r = 0; r < WR; ++r) mn[r] = 3.0e38f;
    for (int q0 = 0; q0 < Ms; q0 += 64) {
        int t_ = q0 + lane;
        bool act = t_ < Ms;
        int idx = fb ? t_ : (int)sidx[wave][act ? t_ : 0];
        float4 c = act ? xsb[idx] : make_float4(0.0f, 0.0f, 0.0f, 3.0e38f);
#pragma unroll
        for (int r = 0; r < WR; ++r) mn[r] = fminf(mn[r], vkey(xi[r], c));
    }

    // ---- final tau: exact 16th smallest of the 64 lane-minima ----
#pragma unroll
    for (int r = 0; r < WR; ++r) vw[r * 64 + lane] = mn[r];
    __syncthreads();
    float tau[WR];
#pragma unroll
    for (int r = 0; r < WR; ++r) {
        float mine = mn[r];
        int rk = 0;
        const float4* vm4 = (const float4*)(vw + r * 64);
#pragma unroll
        for (int q = 0; q < 16; ++q) {
            float4 vv = vm4[q];
            int j0 = q * 4;
            rk += (vv.x < mine || (vv.x == mine && (j0 + 0) < lane)) ? 1 : 0;
            rk += (vv.y < mine || (vv.y == mine && (j0 + 1) < lane)) ? 1 : 0;
            rk += (vv.z < mine || (vv.z == mine && (j0 + 2) < lane)) ? 1 : 0;
            rk += (vv.w < mine || (vv.w == mine && (j0 + 3) < lane)) ? 1 : 0;
        }
        float v = (rk < KNN) ? mine : -3.0e38f;
#pragma unroll
        for (int o = 32; o > 0; o >>= 1) v = fmaxf(v, __shfl_xor(v, o));
        tau[r] = v;
    }

    // ---- pass B: ballot-append (v, orig) for v <= tau ----
    int cnt[WR];
#pragma unroll
    for (int r = 0; r < WR; ++r) cnt[r] = 0;
    for (int q0 = 0; q0 < Ms; q0 += 64) {
        int t_ = q0 + lane;
        bool act = t_ < Ms;
        int idx = fb ? t_ : (int)sidx[wave][act ? t_ : 0];
        float4 c = act ? xsb[idx] : make_float4(0.0f, 0.0f, 0.0f, 3.0e38f);
        float fo = act ? (float)oib[idx] : 0.0f;
#pragma unroll
        for (int r = 0; r < WR; ++r) {
            float v = vkey(xi[r], c);
            bool p = (v <= tau[r]);
            unsigned long long m = __ballot(p);
            if (m) {
                if (p) {
                    int pos = cnt[r] + mbcnt64(m);
                    if (pos < CAP) buf[wave][r][pos] = make_float2(v, fo);
                }
                cnt[r] += (int)__popcll(m);
            }
        }
    }

    __syncthreads();

    // ---- phase 3: exact top-16 by (v, orig) rank count ----
#pragma unroll
    for (int rr = 0; rr < WR; ++rr) {
        int n = cnt[rr];
        n = (n < CAP) ? n : CAP;
        int l1 = lane + 64;
        bool v0 = (lane < n), v1 = (l1 < n);
        float2 e0 = buf[wave][rr][v0 ? lane : 0];
        float2 e1 = buf[wave][rr][v1 ? l1 : 0];
        int r0 = 0, r1 = 0;
        for (int j = 0; j < n; ++j) {
            float2 fj = buf[wave][rr][j];
            r0 += (fj.x < e0.x || (fj.x == e0.x && fj.y < e0.y)) ? 1 : 0;
            r1 += (fj.x < e1.x || (fj.x == e1.x && fj.y < e1.y)) ? 1 : 0;
        }
        size_t grow = (size_t)(b * NPTS + orow[rr]) * KNN;
        if (v0 && r0 < KNN) ibuf[grow + r0] = (unsigned short)(int)e0.y;
        if (v1 && r1 < KNN) ibuf[grow + r1] = (unsigned short)(int)e1.y;
    }
}

__global__ __launch_bounds__(256) void k3_moments(const float4* __restrict__ xq,
                                                  const unsigned short* __restrict__ ibuf,
                                                  double* __restrict__ stats) {
    __shared__ float red[4][54];
    int p = blockIdx.x * 256 + threadIdx.x;
    int b = p >> 13;
    const float4* xb = xq + b * NPTS;
    const unsigned short* ib = ibuf + (size_t)p * KNN;
    float4 xi = xb[p & (NPTS - 1)];

    float acc[54];
#pragma unroll
    for (int i = 0; i < 54; ++i) acc[i] = 0.0f;

#pragma unroll
    for (int k = 0; k < KNN; ++k) {
        int j = ib[k];
        float4 cj = xb[j];
        float f[9] = {xi.x, xi.y, xi.z, cj.x - xi.x, cj.y - xi.y, cj.z - xi.z, cj.x, cj.y, cj.z};
        int t = 9;
#pragma unroll
        for (int a = 0; a < 9; ++a) {
            acc[a] += f[a];
#pragma unroll
            for (int c = a; c < 9; ++c) { acc[t] += f[a] * f[c]; ++t; }
        }
    }

#pragma unroll
    for (int i = 0; i < 54; ++i) {
        float v = acc[i];
        for (int o = 32; o > 0; o >>= 1) v += __shfl_down(v, o);
        acc[i] = v;
    }
    int lane = threadIdx.x & 63;
    int wv = threadIdx.x >> 6;
    if (lane == 0) {
#pragma unroll
        for (int i = 0; i < 54; ++i) red[wv][i] = acc[i];
    }
    __syncthreads();
    if (threadIdx.x < 54) {
        float s = red[0][threadIdx.x] + red[1][threadIdx.x] + red[2][threadIdx.x] + red[3][threadIdx.x];
        atomicAdd(&stats[threadIdx.x], (double)s);
    }
}

__global__ void k4_finalize(const double* __restrict__ stats, const float* __restrict__ W,
                            const float* __restrict__ bias, const float* __restrict__ gamma,
                            const float* __restrict__ beta, float* __restrict__ ss) {
    int d = threadIdx.x;
    if (d >= DCH) return;
    const double M = (double)NB * NPTS * KNN;  // 524288
    double w[9];
    for (int c = 0; c < 9; ++c) w[c] = (double)W[c * DCH + d];
    double mf[9];
    for (int a = 0; a < 9; ++a) mf[a] = stats[a] / M;
    double q1 = 0.0;
    for (int a = 0; a < 9; ++a) q1 += mf[a] * w[a];
    double q2 = 0.0;
    int t = 0;
    for (int a = 0; a < 9; ++a) {
        for (int c = a; c < 9; ++c) {
            double pv = stats[9 + t] / M;
            double term = pv * w[a] * w[c];
            q2 += (a == c) ? term : 2.0 * term;
            ++t;
        }
    }
    double bd = (double)bias[d];
    double mean = q1 + bd;
    double ehh = q2 + 2.0 * bd * q1 + bd * bd;
    double var = ehh - mean * mean;
    double sc = (double)gamma[d] / sqrt(var + 1e-5);
    double sh = (double)beta[d] + sc * (bd - mean);
    ss[d] = (float)sc;
    ss[DCH + d] = (float)sh;
}

__global__ __launch_bounds__(256) void k5_out(const float4* __restrict__ xq,
                                              const unsigned short* __restrict__ ibuf,
                                              const float* __restrict__ W, const float* __restrict__ ss,
                                              float* __restrict__ out) {
    __shared__ float Ws[9 * DCH];
    __shared__ float scs[DCH], shs[DCH];
    for (int i = threadIdx.x; i < 9 * DCH; i += 256) Ws[i] = W[i];
    if (threadIdx.x < DCH) {
        scs[threadIdx.x] = ss[threadIdx.x];
        shs[threadIdx.x] = ss[DCH + threadIdx.x];
    }
    __syncthreads();

    int pt = blockIdx.x * 32 + (threadIdx.x >> 3);
    int oc = (threadIdx.x & 7) * 8;
    int b = pt >> 13;
    const float4* xb = xq + b * NPTS;
    float4 xi = xb[pt & (NPTS - 1)];

    float w[9][8];
#pragma unroll
    for (int c = 0; c < 9; ++c)
#pragma unroll
        for (int d = 0; d < 8; ++d) w[c][d] = Ws[c * DCH + oc + d];
    float sc[8], sh[8], y[8];
#pragma unroll
    for (int d = 0; d < 8; ++d) {
        sc[d] = scs[oc + d];
        sh[d] = shs[oc + d];
        y[d] = 0.0f;
    }

    const unsigned short* ib = ibuf + (size_t)pt * KNN;
#pragma unroll
    for (int k = 0; k < KNN; ++k) {
        int j = ib[k];
        float4 cj = xb[j];
        float f[9] = {xi.x, xi.y, xi.z, cj.x - xi.x, cj.y - xi.y, cj.z - xi.z, cj.x, cj.y, cj.z};
        float h[8];
#pragma unroll
        for (int d = 0; d < 8; ++d) h[d] = 0.0f;
#pragma unroll
        for (int c = 0; c < 9; ++c)
#pragma unroll
            for (int d = 0; d < 8; ++d) h[d] = __fmaf_rn(f[c], w[c][d], h[d]);
#pragma unroll
        for (int d = 0; d < 8; ++d) {
            float v = __fmaf_rn(sc[d], h[d], sh[d]);
            y[d] = fmaxf(y[d], fmaxf(v, 0.0f));
        }
    }
    float4* o4 = (float4*)(out + (size_t)pt * DCH + oc);
    o4[0] = make_float4(y[0], y[1], y[2], y[3]);
    o4[1] = make_float4(y[4], y[5], y[6], y[7]);
}

extern "C" void kernel_launch(void* const* d_in, const int* in_sizes, int n_in,
                              void* d_out, int out_size, void* d_ws, size_t ws_size,
                              hipStream_t stream) {
    const float* x = (const float*)d_in[0];
    const float* W = (const float*)d_in[1];
    const float* bias = (const float*)d_in[2];
    const float* gamma = (const float*)d_in[3];
    const float* beta = (const float*)d_in[4];
    float* out = (float*)d_out;
    char* ws = (char*)d_ws;

    float4* xq = (float4*)(ws + WS_XQ);
    float4* xss = (float4*)(ws + WS_XS);
    unsigned short* oidx = (unsigned short*)(ws + WS_OI);
    unsigned short* ibuf = (unsigned short*)(ws + WS_IB);
    int* cellP = (int*)(ws + WS_CP);
    double* stats = (double*)(ws + WS_ST);
    float* ss = (float*)(ws + WS_SS);

    hipMemsetAsync(cellP, 0, NB * NC * sizeof(int), stream);
    hipMemsetAsync(stats, 0, 54 * sizeof(double), stream);
    k1_prep<<<128, 256, 0, stream>>>(x, xq, cellP);
    k0b_prefix<<<NB, 1024, 0, stream>>>(cellP);
    k0c_scatter<<<128, 256, 0, stream>>>(x, cellP, xss, oidx);
    k2_knn<<<1024, 256, 0, stream>>>(xq, xss, oidx, cellP, ibuf);
    k3_moments<<<128, 256, 0, stream>>>(xq, ibuf, stats);
    k4_finalize<<<1, 64, 0, stream>>>(stats, W, bias, gamma, beta, ss);
    k5_out<<<1024, 256, 0, stream>>>(xq, ibuf, W, ss, out);
}